// Round 21
// baseline (558.168 us; speedup 1.0000x reference)
//
#include <hip/hip_runtime.h>
#include <hip/hip_bf16.h>
#include <cstdint>
#include <cstddef>

#define B_TOK 8192
#define DIM   1024
#define HID   4096
#define NEXP  8
#define MAXSLOT 17408  // B_TOK*2 + NEXP*127 padding (128-aligned expert offsets)

typedef __bf16 bf16x8 __attribute__((ext_vector_type(8)));
typedef float  f32x4  __attribute__((ext_vector_type(4)));

__device__ __forceinline__ void load_lds16(const void* g, void* l) {
  __builtin_amdgcn_global_load_lds(
      (const __attribute__((address_space(1))) void*)g,
      (__attribute__((address_space(3))) void*)l, 16, 0, 0);
}

// fp32 -> bf16 RNE
__device__ __forceinline__ uint16_t f2b(float f) {
  uint32_t u = __builtin_bit_cast(uint32_t, f);
  return (uint16_t)((u + 0x7FFFu + ((u >> 16) & 1u)) >> 16);
}
__device__ __forceinline__ float b2f(uint32_t hbits) {
  uint32_t u = hbits << 16;
  return __builtin_bit_cast(float, u);
}

// ---------------- init ----------------
__global__ void init_kernel(int* __restrict__ rows16k, int* __restrict__ counts,
                            int* __restrict__ cursor, float* __restrict__ zeropad) {
  int i = blockIdx.x * 256 + threadIdx.x;
  if (i < MAXSLOT) rows16k[i] = -1;
  if (i < NEXP) { counts[i] = 0; cursor[i] = 0; }
  if (i < 16) zeropad[i] = 0.f;
}

// ---------------- merged W1+W2 transpose-convert (vectorized) ----------------
// out[n][m] = bf16(in[m][n]) per expert slab. Tile 64x64, 256 threads.
// grid(64, 64, 16): x = n-tile, y = m-tile, z = which*8+e; out-of-range blocks return.
__global__ void transpose_cvt2_kernel(const float* __restrict__ W1, uint16_t* __restrict__ W1b,
                                      const float* __restrict__ W2, uint16_t* __restrict__ W2b) {
  const int which = blockIdx.z >> 3, e = blockIdx.z & 7;
  const int M = which ? HID : DIM;   // input rows
  const int N = which ? DIM : HID;   // input cols
  if (blockIdx.x * 64 >= N || blockIdx.y * 64 >= M) return;
  const float* in = (which ? W2 : W1) + (size_t)e * M * N;
  uint16_t* out = (which ? W2b : W1b) + (size_t)e * M * N;

  __shared__ uint16_t tile[64][66];
  const int t = threadIdx.x;
  const int lr = t & 15, lw = t >> 4;

#pragma unroll
  for (int i = 0; i < 4; i++) {
    const int ml = lw + i * 16;
    const int nl = lr * 4;
    float4 v = *(const float4*)(in + (size_t)(blockIdx.y * 64 + ml) * N + blockIdx.x * 64 + nl);
    uint64_t p = (uint64_t)f2b(v.x) | ((uint64_t)f2b(v.y) << 16) |
                 ((uint64_t)f2b(v.z) << 32) | ((uint64_t)f2b(v.w) << 48);
    *(uint64_t*)&tile[ml][nl] = p;
  }
  __syncthreads();
#pragma unroll
  for (int i = 0; i < 4; i++) {
    const int nl = lw + i * 16;
    const int ml = lr * 4;
    uint64_t p = (uint64_t)tile[ml + 0][nl] | ((uint64_t)tile[ml + 1][nl] << 16) |
                 ((uint64_t)tile[ml + 2][nl] << 32) | ((uint64_t)tile[ml + 3][nl] << 48);
    *(uint64_t*)(out + (size_t)(blockIdx.x * 64 + nl) * M + blockIdx.y * 64 + ml) = p;
  }
}

// ---------------- router (vectorized; NO atomics; + x->bf16 conversion fused) -------
__global__ void router_kernel(const float* __restrict__ x, const float* __restrict__ Wr,
                              const float* __restrict__ br, int* __restrict__ top_i,
                              float* __restrict__ top_w, uint16_t* __restrict__ xb) {
  const int wave = threadIdx.x >> 6, lane = threadIdx.x & 63;
  const int b = blockIdx.x * 4 + wave;
  const float* xr = x + (size_t)b * DIM;
  uint16_t* xbr = xb + (size_t)b * DIM;
  float acc[NEXP];
#pragma unroll
  for (int e = 0; e < NEXP; e++) acc[e] = 0.f;
#pragma unroll
  for (int i = 0; i < 4; i++) {
    const int d0 = i * 256 + lane * 4;
    float4 xv = *(const float4*)(xr + d0);
    uint64_t p = (uint64_t)f2b(xv.x) | ((uint64_t)f2b(xv.y) << 16) |
                 ((uint64_t)f2b(xv.z) << 32) | ((uint64_t)f2b(xv.w) << 48);
    *(uint64_t*)(xbr + d0) = p;
    float xs[4] = {xv.x, xv.y, xv.z, xv.w};
#pragma unroll
    for (int j = 0; j < 4; j++) {
      const float4* wr = (const float4*)(Wr + (size_t)(d0 + j) * NEXP);
      float4 w0 = wr[0], w1 = wr[1];
      acc[0] += xs[j] * w0.x; acc[1] += xs[j] * w0.y;
      acc[2] += xs[j] * w0.z; acc[3] += xs[j] * w0.w;
      acc[4] += xs[j] * w1.x; acc[5] += xs[j] * w1.y;
      acc[6] += xs[j] * w1.z; acc[7] += xs[j] * w1.w;
    }
  }
#pragma unroll
  for (int e = 0; e < NEXP; e++)
#pragma unroll
    for (int off = 32; off; off >>= 1) acc[e] += __shfl_xor(acc[e], off);
  if (lane == 0) {
    float l[NEXP];
#pragma unroll
    for (int e = 0; e < NEXP; e++) l[e] = acc[e] + br[e];
    int i0 = 0; float v0 = l[0];
#pragma unroll
    for (int e = 1; e < NEXP; e++) if (l[e] > v0) { v0 = l[e]; i0 = e; }
    int i1 = -1; float v1 = -3.4e38f;
#pragma unroll
    for (int e = 0; e < NEXP; e++) if (e != i0 && l[e] > v1) { v1 = l[e]; i1 = e; }
    float w0 = 1.f / (1.f + expf(v1 - v0));
    float w1 = 1.f - w0;
    top_i[b * 2 + 0] = i0; top_i[b * 2 + 1] = i1;
    top_w[b * 2 + 0] = w0; top_w[b * 2 + 1] = w1;
  }
}

// wave-aggregated expert histogram. grid(B_TOK/256), block 256.
__global__ void count_kernel(const int* __restrict__ top_i, int* __restrict__ counts) {
  const int b = blockIdx.x * 256 + threadIdx.x;
  const int lane = threadIdx.x & 63;
#pragma unroll
  for (int k = 0; k < 2; k++) {
    const int e = top_i[b * 2 + k];
#pragma unroll
    for (int ex = 0; ex < NEXP; ex++) {
      unsigned long long m = __ballot(e == ex);
      if (e == ex) {
        int leader = __ffsll((long long)m) - 1;
        if (lane == leader) atomicAdd(&counts[ex], __popcll(m));
      }
    }
  }
}

__global__ void offsets_kernel(const int* __restrict__ counts, int* __restrict__ off_p) {
  int o = 0;
  for (int e = 0; e < NEXP; e++) { off_p[e] = o; o += (counts[e] + 127) & ~127; }
  off_p[NEXP] = o;
}

// wave-aggregated scatter
__global__ void scatter_kernel(const int* __restrict__ top_i, const float* __restrict__ top_w,
                               const int* __restrict__ off_p, int* __restrict__ cursor,
                               int* __restrict__ rows16k, float* __restrict__ wgt,
                               int* __restrict__ slot_of) {
  const int b = blockIdx.x * 256 + threadIdx.x;
  const int lane = threadIdx.x & 63;
#pragma unroll
  for (int k = 0; k < 2; k++) {
    const int e = top_i[b * 2 + k];
    const float w = top_w[b * 2 + k];
    int pos = 0;
#pragma unroll
    for (int ex = 0; ex < NEXP; ex++) {
      unsigned long long m = __ballot(e == ex);
      if (e == ex) {
        int nset = __popcll(m);
        int rank = __popcll(m & ((1ull << lane) - 1ull));
        int leader = __ffsll((long long)m) - 1;
        int base = 0;
        if (lane == leader) base = atomicAdd(&cursor[ex], nset);
        base = __shfl(base, leader);
        pos = off_p[ex] + base + rank;
      }
    }
    rows16k[pos] = b;
    wgt[pos] = w;
    slot_of[b * 2 + k] = pos;
  }
}

// ---------------- 128x128 BK=64 double-buffer counted-vmcnt grouped GEMM, 2 blocks/CU ----
// The one untested config cell: {BK=64 dbuf, counted vmcnt(8), 2 blocks/CU, XCD pin,
// uniform K}. Full-iteration prefetch depth: iter t issues tile t+1's 8 loads then
// waits vmcnt(8) (only tile t) -> steady state has zero load-wait; tile t+1 is in
// flight across both barriers (T4). BK=64 keeps full 128B-line fetches (no R19
// half-line refetch); XCD pin + uniform K keep FETCH compulsory (R13/R18 lessons).
// Buffer (t+2)&1 is only written after the barrier closing COMPUTE(t) -> race-free.
// LDS 64 KiB = 2 buf x (A 16KB | B 16KB). Same verified XOR swizzle as R4-R20.
template<bool GATHER, bool GELU>
__global__ __launch_bounds__(256, 2) void gemm128_kernel(
    const uint16_t* __restrict__ Abase, const uint16_t* __restrict__ Wb,
    const float* __restrict__ bias, const int* __restrict__ rows16k,
    const int* __restrict__ counts, const int* __restrict__ off_p,
    const float* __restrict__ zeropad, uint16_t* __restrict__ outb,
    int Nfull, int Kdim) {
  const int e = blockIdx.x;            // fastest dim -> XCD pinning
  const int ne = counts[e];
  const int rb = blockIdx.z;
  if (rb * 128 >= ne) return;
  const int nbase = blockIdx.y * 128;
  const int sbase = off_p[e] + rb * 128;
  const int nt = Kdim / 64;

  __shared__ __align__(16) uint16_t smem[2 * 2 * 128 * 64];  // 64 KiB: 2 x (A 16K | B 16K)

  const int tid = threadIdx.x;
  const int lane = tid & 63;
  const int wid = tid >> 6;
  const int wm = wid >> 1, wn = wid & 1;
  const int lr = lane & 15, lh = lane >> 4;
  const int swz8 = (((tid & 7) ^ ((tid >> 3) & 7)) * 8);

  const uint16_t* srcA[4]; int stA[4];
  const uint16_t* srcB[4];
#pragma unroll
  for (int is = 0; is < 4; is++) {
    const int r = (tid >> 3) + is * 32;
    if (GATHER) {
      int tok = rows16k[sbase + r];
      srcA[is] = (tok >= 0) ? (Abase + (size_t)tok * Kdim + swz8) : (const uint16_t*)zeropad;
      stA[is] = (tok >= 0) ? 64 : 0;
    } else {
      srcA[is] = Abase + (size_t)(sbase + r) * Kdim + swz8;
      stA[is] = 64;
    }
    srcB[is] = Wb + ((size_t)e * Nfull + nbase + r) * Kdim + swz8;
  }

  f32x4 acc[4][4];
#pragma unroll
  for (int mi = 0; mi < 4; mi++)
#pragma unroll
    for (int ni = 0; ni < 4; ni++) acc[mi][ni] = (f32x4){0.f, 0.f, 0.f, 0.f};

  auto STAGE = [&](int buf) {
    uint16_t* dA = &smem[buf * 16384];
    uint16_t* dB = dA + 8192;
#pragma unroll
    for (int is = 0; is < 4; is++) {
      load_lds16(srcA[is], dA + (is * 256 + tid) * 8);
      load_lds16(srcB[is], dB + (is * 256 + tid) * 8);
      srcA[is] += stA[is]; srcB[is] += 64;
    }
  };

  STAGE(0);   // prologue: tile 0's 8 loads in flight

  for (int t = 0; t < nt; ++t) {
    const int cb = t & 1;
    if (t + 1 < nt) {
      STAGE(cb ^ 1);                                   // 16 outstanding
      asm volatile("s_waitcnt vmcnt(8)" ::: "memory"); // tile t landed; t+1 in flight
    } else {
      asm volatile("s_waitcnt vmcnt(0)" ::: "memory"); // last tile (in flight a full iter)
    }
    __builtin_amdgcn_s_barrier();   // all waves: tile t staged

    const uint16_t* sA = &smem[cb * 16384];
    const uint16_t* sB = sA + 8192;
#pragma unroll
    for (int kk = 0; kk < 2; kk++) {
      bf16x8 afr[4], bfr[4];
#pragma unroll
      for (int ni = 0; ni < 4; ni++) {
        const int row = wn * 64 + ni * 16 + lr;
        const int c = (kk * 4 + lh) ^ (lr & 7);
        bfr[ni] = *(const bf16x8*)&sB[row * 64 + c * 8];
      }
#pragma unroll
      for (int mi = 0; mi < 4; mi++) {
        const int row = wm * 64 + mi * 16 + lr;
        const int c = (kk * 4 + lh) ^ (lr & 7);
        afr[mi] = *(const bf16x8*)&sA[row * 64 + c * 8];
      }
      __builtin_amdgcn_s_setprio(1);
#pragma unroll
      for (int mi = 0; mi < 4; mi++)
#pragma unroll
        for (int ni = 0; ni < 4; ni++)
          acc[mi][ni] = __builtin_amdgcn_mfma_f32_16x16x32_bf16(afr[mi], bfr[ni], acc[mi][ni], 0, 0, 0);
      __builtin_amdgcn_s_setprio(0);
    }
    __builtin_amdgcn_s_barrier();   // reads of buf cb done -> iter t+1 may overwrite it
  }

  float biasv[4];
#pragma unroll
  for (int ni = 0; ni < 4; ni++)
    biasv[ni] = bias[(size_t)e * Nfull + nbase + wn * 64 + ni * 16 + lr];
#pragma unroll
  for (int mi = 0; mi < 4; mi++)
#pragma unroll
    for (int ni = 0; ni < 4; ni++)
#pragma unroll
      for (int r = 0; r < 4; r++) {
        const int row = wm * 64 + mi * 16 + lh * 4 + r;
        const int col = nbase + wn * 64 + ni * 16 + lr;
        float t = acc[mi][ni][r] + biasv[ni];
        float g;
        if (GELU) {
          // tanh-form GELU via exp2: g = t - t/(2^(t*(c1 + c2*t^2)) + 1)
          float t2 = t * t;
          float v = t * fmaf(0.1029437f, t2, 2.3022085f);
          float ex = exp2f(v);
          float rr = 1.0f / (ex + 1.0f);
          g = t - t * rr;
        } else {
          g = t;
        }
        outb[(size_t)(sbase + row) * Nfull + col] = f2b(g);
      }
}

// ---------------- combine: out[b] = w0*y[slot0] + w1*y[slot1] ----------------
__global__ void combine_kernel(const uint16_t* __restrict__ y, const int* __restrict__ slot_of,
                               const float* __restrict__ top_w, float* __restrict__ out) {
  const int b = blockIdx.x;
  const int t = threadIdx.x;
  const int s0 = slot_of[b * 2], s1 = slot_of[b * 2 + 1];
  const float w0 = top_w[b * 2], w1 = top_w[b * 2 + 1];
  uint64_t p0 = *(const uint64_t*)(y + (size_t)s0 * DIM + t * 4);
  uint64_t p1 = *(const uint64_t*)(y + (size_t)s1 * DIM + t * 4);
  float4 r;
  r.x = w0 * b2f((uint32_t)(p0 >> 0) & 0xFFFFu)  + w1 * b2f((uint32_t)(p1 >> 0) & 0xFFFFu);
  r.y = w0 * b2f((uint32_t)(p0 >> 16) & 0xFFFFu) + w1 * b2f((uint32_t)(p1 >> 16) & 0xFFFFu);
  r.z = w0 * b2f((uint32_t)(p0 >> 32) & 0xFFFFu) + w1 * b2f((uint32_t)(p1 >> 32) & 0xFFFFu);
  r.w = w0 * b2f((uint32_t)(p0 >> 48) & 0xFFFFu) + w1 * b2f((uint32_t)(p1 >> 48) & 0xFFFFu);
  *(float4*)(out + (size_t)b * DIM + t * 4) = r;
}

// ---------------- launch ----------------
extern "C" void kernel_launch(void* const* d_in, const int* in_sizes, int n_in,
                              void* d_out, int out_size, void* d_ws, size_t ws_size,
                              hipStream_t stream) {
  const float* x  = (const float*)d_in[0];
  const float* Wr = (const float*)d_in[1];
  const float* br = (const float*)d_in[2];
  const float* W1 = (const float*)d_in[3];
  const float* b1 = (const float*)d_in[4];
  const float* W2 = (const float*)d_in[5];
  const float* b2 = (const float*)d_in[6];
  float* out = (float*)d_out;

  char* ws = (char*)d_ws;
  uint16_t* W1b = (uint16_t*)ws; ws += (size_t)NEXP * HID * DIM * 2;   // 64 MB
  uint16_t* W2b = (uint16_t*)ws; ws += (size_t)NEXP * DIM * HID * 2;   // 64 MB
  uint16_t* xb  = (uint16_t*)ws; ws += (size_t)B_TOK * DIM * 2;        // 16 MB
  uint16_t* h   = (uint16_t*)ws; ws += (size_t)MAXSLOT * HID * 2;      // 143 MB
  uint16_t* yb  = (uint16_t*)ws; ws += (size_t)MAXSLOT * DIM * 2;      // 36 MB
  int*   top_i  = (int*)ws;   ws += (size_t)B_TOK * 2 * 4;
  float* top_w  = (float*)ws; ws += (size_t)B_TOK * 2 * 4;
  int*   slot_of= (int*)ws;   ws += (size_t)B_TOK * 2 * 4;
  int*   rows16k= (int*)ws;   ws += (size_t)MAXSLOT * 4;
  float* wgt    = (float*)ws; ws += (size_t)MAXSLOT * 4;
  int*   counts = (int*)ws;   ws += 64;
  int*   cursor = (int*)ws;   ws += 64;
  int*   off_p  = (int*)ws;   ws += 64;
  float* zeropad= (float*)ws; ws += 64;

  init_kernel<<<dim3((MAXSLOT + 255) / 256), dim3(256), 0, stream>>>(rows16k, counts, cursor, zeropad);
  transpose_cvt2_kernel<<<dim3(64, 64, 16), dim3(256), 0, stream>>>(W1, W1b, W2, W2b);
  router_kernel<<<dim3(B_TOK / 4), dim3(256), 0, stream>>>(x, Wr, br, top_i, top_w, xb);
  count_kernel<<<dim3(B_TOK / 256), dim3(256), 0, stream>>>(top_i, counts);
  offsets_kernel<<<dim3(1), dim3(1), 0, stream>>>(counts, off_p);
  scatter_kernel<<<dim3(B_TOK / 256), dim3(256), 0, stream>>>(top_i, top_w, off_p, cursor, rows16k, wgt, slot_of);
  // gemm1: h = gelu(gather(x) @ W1^T + b1)   [M=slots, N=HID, K=DIM]
  // grid(x=expert -> XCD pin, y=N-tiles, z=M-tiles)
  gemm128_kernel<true, true><<<dim3(NEXP, HID / 128, MAXSLOT / 128), dim3(256), 0, stream>>>(
      xb, W1b, b1, rows16k, counts, off_p, zeropad, h, HID, DIM);
  // gemm2: y = h @ W2^T + b2                  [M=slots, N=DIM, K=HID]
  gemm128_kernel<false, false><<<dim3(NEXP, DIM / 128, MAXSLOT / 128), dim3(256), 0, stream>>>(
      h, W2b, b2, rows16k, counts, off_p, zeropad, yb, DIM, HID);
  combine_kernel<<<dim3(B_TOK), dim3(256), 0, stream>>>(yb, slot_of, top_w, out);
}

// Round 22
// 548.532 us; speedup vs baseline: 1.0176x; 1.0176x over previous
//
#include <hip/hip_runtime.h>
#include <hip/hip_bf16.h>
#include <cstdint>
#include <cstddef>

#define B_TOK 8192
#define DIM   1024
#define HID   4096
#define NEXP  8
#define MAXSLOT 17408  // B_TOK*2 + NEXP*127 padding (128-aligned expert offsets)

typedef __bf16 bf16x8 __attribute__((ext_vector_type(8)));
typedef float  f32x4  __attribute__((ext_vector_type(4)));

__device__ __forceinline__ void load_lds16(const void* g, void* l) {
  __builtin_amdgcn_global_load_lds(
      (const __attribute__((address_space(1))) void*)g,
      (__attribute__((address_space(3))) void*)l, 16, 0, 0);
}

// fp32 -> bf16 RNE
__device__ __forceinline__ uint16_t f2b(float f) {
  uint32_t u = __builtin_bit_cast(uint32_t, f);
  return (uint16_t)((u + 0x7FFFu + ((u >> 16) & 1u)) >> 16);
}
__device__ __forceinline__ float b2f(uint32_t hbits) {
  uint32_t u = hbits << 16;
  return __builtin_bit_cast(float, u);
}

// ---------------- init ----------------
__global__ void init_kernel(int* __restrict__ rows16k, int* __restrict__ counts,
                            int* __restrict__ cursor, float* __restrict__ zeropad) {
  int i = blockIdx.x * 256 + threadIdx.x;
  if (i < MAXSLOT) rows16k[i] = -1;
  if (i < NEXP) { counts[i] = 0; cursor[i] = 0; }
  if (i < 16) zeropad[i] = 0.f;
}

// ---------------- merged W1+W2 transpose-convert (vectorized) ----------------
// out[n][m] = bf16(in[m][n]) per expert slab. Tile 64x64, 256 threads.
// grid(64, 64, 16): x = n-tile, y = m-tile, z = which*8+e; out-of-range blocks return.
__global__ void transpose_cvt2_kernel(const float* __restrict__ W1, uint16_t* __restrict__ W1b,
                                      const float* __restrict__ W2, uint16_t* __restrict__ W2b) {
  const int which = blockIdx.z >> 3, e = blockIdx.z & 7;
  const int M = which ? HID : DIM;   // input rows
  const int N = which ? DIM : HID;   // input cols
  if (blockIdx.x * 64 >= N || blockIdx.y * 64 >= M) return;
  const float* in = (which ? W2 : W1) + (size_t)e * M * N;
  uint16_t* out = (which ? W2b : W1b) + (size_t)e * M * N;

  __shared__ uint16_t tile[64][66];
  const int t = threadIdx.x;
  const int lr = t & 15, lw = t >> 4;

#pragma unroll
  for (int i = 0; i < 4; i++) {
    const int ml = lw + i * 16;
    const int nl = lr * 4;
    float4 v = *(const float4*)(in + (size_t)(blockIdx.y * 64 + ml) * N + blockIdx.x * 64 + nl);
    uint64_t p = (uint64_t)f2b(v.x) | ((uint64_t)f2b(v.y) << 16) |
                 ((uint64_t)f2b(v.z) << 32) | ((uint64_t)f2b(v.w) << 48);
    *(uint64_t*)&tile[ml][nl] = p;
  }
  __syncthreads();
#pragma unroll
  for (int i = 0; i < 4; i++) {
    const int nl = lw + i * 16;
    const int ml = lr * 4;
    uint64_t p = (uint64_t)tile[ml + 0][nl] | ((uint64_t)tile[ml + 1][nl] << 16) |
                 ((uint64_t)tile[ml + 2][nl] << 32) | ((uint64_t)tile[ml + 3][nl] << 48);
    *(uint64_t*)(out + (size_t)(blockIdx.x * 64 + nl) * M + blockIdx.y * 64 + ml) = p;
  }
}

// ---------------- router (vectorized; NO atomics; + x->bf16 conversion fused) -------
__global__ void router_kernel(const float* __restrict__ x, const float* __restrict__ Wr,
                              const float* __restrict__ br, int* __restrict__ top_i,
                              float* __restrict__ top_w, uint16_t* __restrict__ xb) {
  const int wave = threadIdx.x >> 6, lane = threadIdx.x & 63;
  const int b = blockIdx.x * 4 + wave;
  const float* xr = x + (size_t)b * DIM;
  uint16_t* xbr = xb + (size_t)b * DIM;
  float acc[NEXP];
#pragma unroll
  for (int e = 0; e < NEXP; e++) acc[e] = 0.f;
#pragma unroll
  for (int i = 0; i < 4; i++) {
    const int d0 = i * 256 + lane * 4;
    float4 xv = *(const float4*)(xr + d0);
    uint64_t p = (uint64_t)f2b(xv.x) | ((uint64_t)f2b(xv.y) << 16) |
                 ((uint64_t)f2b(xv.z) << 32) | ((uint64_t)f2b(xv.w) << 48);
    *(uint64_t*)(xbr + d0) = p;
    float xs[4] = {xv.x, xv.y, xv.z, xv.w};
#pragma unroll
    for (int j = 0; j < 4; j++) {
      const float4* wr = (const float4*)(Wr + (size_t)(d0 + j) * NEXP);
      float4 w0 = wr[0], w1 = wr[1];
      acc[0] += xs[j] * w0.x; acc[1] += xs[j] * w0.y;
      acc[2] += xs[j] * w0.z; acc[3] += xs[j] * w0.w;
      acc[4] += xs[j] * w1.x; acc[5] += xs[j] * w1.y;
      acc[6] += xs[j] * w1.z; acc[7] += xs[j] * w1.w;
    }
  }
#pragma unroll
  for (int e = 0; e < NEXP; e++)
#pragma unroll
    for (int off = 32; off; off >>= 1) acc[e] += __shfl_xor(acc[e], off);
  if (lane == 0) {
    float l[NEXP];
#pragma unroll
    for (int e = 0; e < NEXP; e++) l[e] = acc[e] + br[e];
    int i0 = 0; float v0 = l[0];
#pragma unroll
    for (int e = 1; e < NEXP; e++) if (l[e] > v0) { v0 = l[e]; i0 = e; }
    int i1 = -1; float v1 = -3.4e38f;
#pragma unroll
    for (int e = 0; e < NEXP; e++) if (e != i0 && l[e] > v1) { v1 = l[e]; i1 = e; }
    float w0 = 1.f / (1.f + expf(v1 - v0));
    float w1 = 1.f - w0;
    top_i[b * 2 + 0] = i0; top_i[b * 2 + 1] = i1;
    top_w[b * 2 + 0] = w0; top_w[b * 2 + 1] = w1;
  }
}

// wave-aggregated expert histogram. grid(B_TOK/256), block 256.
__global__ void count_kernel(const int* __restrict__ top_i, int* __restrict__ counts) {
  const int b = blockIdx.x * 256 + threadIdx.x;
  const int lane = threadIdx.x & 63;
#pragma unroll
  for (int k = 0; k < 2; k++) {
    const int e = top_i[b * 2 + k];
#pragma unroll
    for (int ex = 0; ex < NEXP; ex++) {
      unsigned long long m = __ballot(e == ex);
      if (e == ex) {
        int leader = __ffsll((long long)m) - 1;
        if (lane == leader) atomicAdd(&counts[ex], __popcll(m));
      }
    }
  }
}

__global__ void offsets_kernel(const int* __restrict__ counts, int* __restrict__ off_p) {
  int o = 0;
  for (int e = 0; e < NEXP; e++) { off_p[e] = o; o += (counts[e] + 127) & ~127; }
  off_p[NEXP] = o;
}

// wave-aggregated scatter
__global__ void scatter_kernel(const int* __restrict__ top_i, const float* __restrict__ top_w,
                               const int* __restrict__ off_p, int* __restrict__ cursor,
                               int* __restrict__ rows16k, float* __restrict__ wgt,
                               int* __restrict__ slot_of) {
  const int b = blockIdx.x * 256 + threadIdx.x;
  const int lane = threadIdx.x & 63;
#pragma unroll
  for (int k = 0; k < 2; k++) {
    const int e = top_i[b * 2 + k];
    const float w = top_w[b * 2 + k];
    int pos = 0;
#pragma unroll
    for (int ex = 0; ex < NEXP; ex++) {
      unsigned long long m = __ballot(e == ex);
      if (e == ex) {
        int nset = __popcll(m);
        int rank = __popcll(m & ((1ull << lane) - 1ull));
        int leader = __ffsll((long long)m) - 1;
        int base = 0;
        if (lane == leader) base = atomicAdd(&cursor[ex], nset);
        base = __shfl(base, leader);
        pos = off_p[ex] + base + rank;
      }
    }
    rows16k[pos] = b;
    wgt[pos] = w;
    slot_of[b * 2 + k] = pos;
  }
}

// ---------------- 128x128 BK=64 single-buffer grouped GEMM, 4 blocks/CU (FINAL) ----
// 256 threads = 4 waves 2(M)x2(N); per-wave output 64x64. LDS 32 KiB single buffer.
// Per K-step: STAGE -> __syncthreads -> COMPUTE -> __syncthreads.
// The lockstep 2-barrier loop IS the cross-block sync that makes the per-XCD L2 a
// shared panel cache: all desync'd variants (R18 stagger, R19 BK32-dbuf, R21
// BK64-dbuf-vmcnt) ballooned FETCH 3.5-5x and lost. 8 schedule variants tested;
// this one wins. Expert->XCD pin (blockIdx.x = expert) keeps FETCH compulsory
// (R12->R13: 666->135 MB). XOR chunk swizzle: store j=(tid&7)^(row&7) pre-applied
// on global source; read c=(kk*4+lh)^(lr&7) -> 0 bank conflicts (verified R4-R20).
template<bool GATHER, bool GELU>
__global__ __launch_bounds__(256, 4) void gemm128_kernel(
    const uint16_t* __restrict__ Abase, const uint16_t* __restrict__ Wb,
    const float* __restrict__ bias, const int* __restrict__ rows16k,
    const int* __restrict__ counts, const int* __restrict__ off_p,
    const float* __restrict__ zeropad, uint16_t* __restrict__ outb,
    int Nfull, int Kdim) {
  const int e = blockIdx.x;            // fastest dim -> XCD pinning
  const int ne = counts[e];
  const int rb = blockIdx.z;
  if (rb * 128 >= ne) return;
  const int nbase = blockIdx.y * 128;
  const int sbase = off_p[e] + rb * 128;
  const int nt = Kdim / 64;

  __shared__ __align__(16) uint16_t smem[2 * 128 * 64];  // 32 KiB: A 16 KB | B 16 KB

  const int tid = threadIdx.x;
  const int lane = tid & 63;
  const int wid = tid >> 6;
  const int wm = wid >> 1, wn = wid & 1;
  const int lr = lane & 15, lh = lane >> 4;
  const int swz8 = (((tid & 7) ^ ((tid >> 3) & 7)) * 8);

  const uint16_t* srcA[4]; int stA[4];
  const uint16_t* srcB[4];
#pragma unroll
  for (int is = 0; is < 4; is++) {
    const int r = (tid >> 3) + is * 32;
    if (GATHER) {
      int tok = rows16k[sbase + r];
      srcA[is] = (tok >= 0) ? (Abase + (size_t)tok * Kdim + swz8) : (const uint16_t*)zeropad;
      stA[is] = (tok >= 0) ? 64 : 0;
    } else {
      srcA[is] = Abase + (size_t)(sbase + r) * Kdim + swz8;
      stA[is] = 64;
    }
    srcB[is] = Wb + ((size_t)e * Nfull + nbase + r) * Kdim + swz8;
  }

  f32x4 acc[4][4];
#pragma unroll
  for (int mi = 0; mi < 4; mi++)
#pragma unroll
    for (int ni = 0; ni < 4; ni++) acc[mi][ni] = (f32x4){0.f, 0.f, 0.f, 0.f};

  for (int t = 0; t < nt; ++t) {
    // STAGE tile t into the single buffer
    uint16_t* dA = &smem[0];
    uint16_t* dB = dA + 8192;
#pragma unroll
    for (int is = 0; is < 4; is++) {
      load_lds16(srcA[is], dA + (is * 256 + tid) * 8);
      load_lds16(srcB[is], dB + (is * 256 + tid) * 8);
      srcA[is] += stA[is]; srcB[is] += 64;
    }
    __syncthreads();   // drain stage (vmcnt(0)) + barrier

    // COMPUTE tile t
#pragma unroll
    for (int kk = 0; kk < 2; kk++) {
      bf16x8 afr[4], bfr[4];
#pragma unroll
      for (int ni = 0; ni < 4; ni++) {
        const int row = wn * 64 + ni * 16 + lr;
        const int c = (kk * 4 + lh) ^ (lr & 7);
        bfr[ni] = *(const bf16x8*)&dB[row * 64 + c * 8];
      }
#pragma unroll
      for (int mi = 0; mi < 4; mi++) {
        const int row = wm * 64 + mi * 16 + lr;
        const int c = (kk * 4 + lh) ^ (lr & 7);
        afr[mi] = *(const bf16x8*)&dA[row * 64 + c * 8];
      }
      __builtin_amdgcn_s_setprio(1);
#pragma unroll
      for (int mi = 0; mi < 4; mi++)
#pragma unroll
        for (int ni = 0; ni < 4; ni++)
          acc[mi][ni] = __builtin_amdgcn_mfma_f32_16x16x32_bf16(afr[mi], bfr[ni], acc[mi][ni], 0, 0, 0);
      __builtin_amdgcn_s_setprio(0);
    }
    __syncthreads();   // all reads done -> next STAGE may overwrite
  }

  float biasv[4];
#pragma unroll
  for (int ni = 0; ni < 4; ni++)
    biasv[ni] = bias[(size_t)e * Nfull + nbase + wn * 64 + ni * 16 + lr];
#pragma unroll
  for (int mi = 0; mi < 4; mi++)
#pragma unroll
    for (int ni = 0; ni < 4; ni++)
#pragma unroll
      for (int r = 0; r < 4; r++) {
        const int row = wm * 64 + mi * 16 + lh * 4 + r;
        const int col = nbase + wn * 64 + ni * 16 + lr;
        float t = acc[mi][ni][r] + biasv[ni];
        float g;
        if (GELU) {
          // tanh-form GELU via exp2: g = t - t/(2^(t*(c1 + c2*t^2)) + 1)
          float t2 = t * t;
          float v = t * fmaf(0.1029437f, t2, 2.3022085f);
          float ex = exp2f(v);
          float rr = 1.0f / (ex + 1.0f);
          g = t - t * rr;
        } else {
          g = t;
        }
        outb[(size_t)(sbase + row) * Nfull + col] = f2b(g);
      }
}

// ---------------- combine: out[b] = w0*y[slot0] + w1*y[slot1] ----------------
__global__ void combine_kernel(const uint16_t* __restrict__ y, const int* __restrict__ slot_of,
                               const float* __restrict__ top_w, float* __restrict__ out) {
  const int b = blockIdx.x;
  const int t = threadIdx.x;
  const int s0 = slot_of[b * 2], s1 = slot_of[b * 2 + 1];
  const float w0 = top_w[b * 2], w1 = top_w[b * 2 + 1];
  uint64_t p0 = *(const uint64_t*)(y + (size_t)s0 * DIM + t * 4);
  uint64_t p1 = *(const uint64_t*)(y + (size_t)s1 * DIM + t * 4);
  float4 r;
  r.x = w0 * b2f((uint32_t)(p0 >> 0) & 0xFFFFu)  + w1 * b2f((uint32_t)(p1 >> 0) & 0xFFFFu);
  r.y = w0 * b2f((uint32_t)(p0 >> 16) & 0xFFFFu) + w1 * b2f((uint32_t)(p1 >> 16) & 0xFFFFu);
  r.z = w0 * b2f((uint32_t)(p0 >> 32) & 0xFFFFu) + w1 * b2f((uint32_t)(p1 >> 32) & 0xFFFFu);
  r.w = w0 * b2f((uint32_t)(p0 >> 48) & 0xFFFFu) + w1 * b2f((uint32_t)(p1 >> 48) & 0xFFFFu);
  *(float4*)(out + (size_t)b * DIM + t * 4) = r;
}

// ---------------- launch ----------------
extern "C" void kernel_launch(void* const* d_in, const int* in_sizes, int n_in,
                              void* d_out, int out_size, void* d_ws, size_t ws_size,
                              hipStream_t stream) {
  const float* x  = (const float*)d_in[0];
  const float* Wr = (const float*)d_in[1];
  const float* br = (const float*)d_in[2];
  const float* W1 = (const float*)d_in[3];
  const float* b1 = (const float*)d_in[4];
  const float* W2 = (const float*)d_in[5];
  const float* b2 = (const float*)d_in[6];
  float* out = (float*)d_out;

  char* ws = (char*)d_ws;
  uint16_t* W1b = (uint16_t*)ws; ws += (size_t)NEXP * HID * DIM * 2;   // 64 MB
  uint16_t* W2b = (uint16_t*)ws; ws += (size_t)NEXP * DIM * HID * 2;   // 64 MB
  uint16_t* xb  = (uint16_t*)ws; ws += (size_t)B_TOK * DIM * 2;        // 16 MB
  uint16_t* h   = (uint16_t*)ws; ws += (size_t)MAXSLOT * HID * 2;      // 143 MB
  uint16_t* yb  = (uint16_t*)ws; ws += (size_t)MAXSLOT * DIM * 2;      // 36 MB
  int*   top_i  = (int*)ws;   ws += (size_t)B_TOK * 2 * 4;
  float* top_w  = (float*)ws; ws += (size_t)B_TOK * 2 * 4;
  int*   slot_of= (int*)ws;   ws += (size_t)B_TOK * 2 * 4;
  int*   rows16k= (int*)ws;   ws += (size_t)MAXSLOT * 4;
  float* wgt    = (float*)ws; ws += (size_t)MAXSLOT * 4;
  int*   counts = (int*)ws;   ws += 64;
  int*   cursor = (int*)ws;   ws += 64;
  int*   off_p  = (int*)ws;   ws += 64;
  float* zeropad= (float*)ws; ws += 64;

  init_kernel<<<dim3((MAXSLOT + 255) / 256), dim3(256), 0, stream>>>(rows16k, counts, cursor, zeropad);
  transpose_cvt2_kernel<<<dim3(64, 64, 16), dim3(256), 0, stream>>>(W1, W1b, W2, W2b);
  router_kernel<<<dim3(B_TOK / 4), dim3(256), 0, stream>>>(x, Wr, br, top_i, top_w, xb);
  count_kernel<<<dim3(B_TOK / 256), dim3(256), 0, stream>>>(top_i, counts);
  offsets_kernel<<<dim3(1), dim3(1), 0, stream>>>(counts, off_p);
  scatter_kernel<<<dim3(B_TOK / 256), dim3(256), 0, stream>>>(top_i, top_w, off_p, cursor, rows16k, wgt, slot_of);
  // gemm1: h = gelu(gather(x) @ W1^T + b1)   [M=slots, N=HID, K=DIM]
  // grid(x=expert -> XCD pin, y=N-tiles, z=M-tiles)
  gemm128_kernel<true, true><<<dim3(NEXP, HID / 128, MAXSLOT / 128), dim3(256), 0, stream>>>(
      xb, W1b, b1, rows16k, counts, off_p, zeropad, h, HID, DIM);
  // gemm2: y = h @ W2^T + b2                  [M=slots, N=DIM, K=HID]
  gemm128_kernel<false, false><<<dim3(NEXP, DIM / 128, MAXSLOT / 128), dim3(256), 0, stream>>>(
      h, W2b, b2, rows16k, counts, off_p, zeropad, yb, DIM, HID);
  combine_kernel<<<dim3(B_TOK), dim3(256), 0, stream>>>(yb, slot_of, top_w, out);
}